// Round 6
// baseline (289.030 us; speedup 1.0000x reference)
//
#include <hip/hip_runtime.h>

// DynamicConv: LN -> GEMM+GLU -> GEMM+softmax(K=31) -> depthwise dynamic conv + residual
// B=8, T=2048, C=1024, H=16, hd=64, K=31.
// R6: GEMM1 drops blanket lgkmcnt(0)+sched_barrier(0) (m141 order-pinning) -> compiler
//     emits fine-grained lgkm waits; conv wls padded [64][36] (16-way write conflict fix).

typedef __bf16 bf16_t;
typedef __attribute__((ext_vector_type(8))) __bf16 bf16x8;
typedef __attribute__((ext_vector_type(4))) __bf16 bf16x4;
typedef __attribute__((ext_vector_type(4))) float f32x4;

__device__ __forceinline__ void gload_lds16(const void* g, void* l) {
  void* gg = const_cast<void*>(g);
  __builtin_amdgcn_global_load_lds(
      (__attribute__((address_space(1))) unsigned int*)gg,
      (__attribute__((address_space(3))) unsigned int*)l, 16, 0, 0);
}

// ---------- weight prep: coalesced LDS-transpose to [N][K] bf16 ----------
__global__ __launch_bounds__(256) void prep_wk(const float* __restrict__ Wk,
                                               bf16_t* __restrict__ WT) {
  __shared__ bf16_t T[64][66];
  int c0 = blockIdx.x * 64;
  int k0 = blockIdx.y * 64;
  int tid = threadIdx.x;
#pragma unroll
  for (int p = 0; p < 4; ++p) {
    int idx = p * 256 + tid;
    int r = idx >> 4;
    int q = idx & 15;
    int strip = q >> 3;
    int col4 = (q & 7) * 4;
    const float* src = Wk + (size_t)(k0 + r) * 2048 + strip * 1024 + (c0 >> 1) + col4;
    float4 v = *(const float4*)src;
#pragma unroll
    for (int j = 0; j < 4; ++j) {
      int cl = (col4 + j) * 2 + strip;
      T[cl][r] = (bf16_t)((&v.x)[j]);
    }
  }
  __syncthreads();
  int c = tid >> 2;
  int kk = (tid & 3) * 16;
#pragma unroll
  for (int u = 0; u < 2; ++u) {
    bf16x8 o;
#pragma unroll
    for (int j = 0; j < 8; ++j) o[j] = T[c][kk + u * 8 + j];
    *(bf16x8*)&WT[(size_t)(c0 + c) * 1024 + k0 + kk + u * 8] = o;
  }
}

// WT2 row n: h = n>>5, kk = n&31; = Wck[:, h*31+kk] (kk<31) else 0.
__global__ __launch_bounds__(256) void prep_wck(const float* __restrict__ Wck,
                                                bf16_t* __restrict__ WT) {
  __shared__ bf16_t T[64][66];
  int n0 = blockIdx.x * 64;
  int k0 = blockIdx.y * 64;
  int tid = threadIdx.x;
#pragma unroll
  for (int p = 0; p < 4; ++p) {
    int idx = p * 256 + tid;
    int r = idx >> 4;
    int q = idx & 15;
#pragma unroll
    for (int j = 0; j < 4; ++j) {
      int nl = q * 4 + j;
      int n = n0 + nl;
      int hh = n >> 5, kk = n & 31;
      float val = 0.f;
      if (kk < 31) val = Wck[(size_t)(k0 + r) * 496 + hh * 31 + kk];
      T[nl][r] = (bf16_t)val;
    }
  }
  __syncthreads();
  int c = tid >> 2;
  int kk = (tid & 3) * 16;
#pragma unroll
  for (int u = 0; u < 2; ++u) {
    bf16x8 o;
#pragma unroll
    for (int j = 0; j < 8; ++j) o[j] = T[c][kk + u * 8 + j];
    *(bf16x8*)&WT[(size_t)(n0 + c) * 1024 + k0 + kk + u * 8] = o;
  }
}

// ---------- layernorm: wave-per-row ----------
__global__ __launch_bounds__(256) void ln_kernel(const float* __restrict__ x,
                                                 const float* __restrict__ gamma,
                                                 const float* __restrict__ beta,
                                                 bf16_t* __restrict__ h) {
  int tid = threadIdx.x;
  int lane = tid & 63;
  int row = blockIdx.x * 4 + (tid >> 6);
  const float* xr = x + (size_t)row * 1024;
  float4 v[4];
#pragma unroll
  for (int u = 0; u < 4; ++u) v[u] = *(const float4*)(xr + u * 256 + lane * 4);
  float s = 0.f;
#pragma unroll
  for (int u = 0; u < 4; ++u) s += v[u].x + v[u].y + v[u].z + v[u].w;
#pragma unroll
  for (int off = 32; off > 0; off >>= 1) s += __shfl_xor(s, off);
  float mu = s * (1.f / 1024.f);
  float s2 = 0.f;
#pragma unroll
  for (int u = 0; u < 4; ++u) {
    float a = v[u].x - mu, b = v[u].y - mu, c = v[u].z - mu, d = v[u].w - mu;
    s2 += a * a + b * b + c * c + d * d;
  }
#pragma unroll
  for (int off = 32; off > 0; off >>= 1) s2 += __shfl_xor(s2, off);
  float rs = rsqrtf(s2 * (1.f / 1024.f) + 1e-5f);
#pragma unroll
  for (int u = 0; u < 4; ++u) {
    float4 gv = *(const float4*)(gamma + u * 256 + lane * 4);
    float4 bv = *(const float4*)(beta + u * 256 + lane * 4);
    bf16x4 o;
    o[0] = (bf16_t)((v[u].x - mu) * rs * gv.x + bv.x);
    o[1] = (bf16_t)((v[u].y - mu) * rs * gv.y + bv.y);
    o[2] = (bf16_t)((v[u].z - mu) * rs * gv.z + bv.z);
    o[3] = (bf16_t)((v[u].w - mu) * rs * gv.w + bv.w);
    *(bf16x4*)&h[(size_t)row * 1024 + u * 256 + lane * 4] = o;
  }
}

// ---------- GEMM1: 256x256 tile, BK=64, 8 waves ----------
// No manual lgkm waits: plain-load ds_reads let the compiler insert fine-grained
// lgkmcnt before each dependent MFMA (m97 behavior). vmcnt asm + barriers keep
// the gload_lds staging ordered; setprio wraps the MFMA clusters (T5).
__global__ __launch_bounds__(512, 2) void gemm256_glu(const bf16_t* __restrict__ Ag,
                                                      const bf16_t* __restrict__ Bg,
                                                      const float* __restrict__ bias,
                                                      bf16_t* __restrict__ outp) {
  extern __shared__ char smem[];
  const int tid = threadIdx.x;
  const int lane = tid & 63;
  const int wid = tid >> 6;
  const int wr = wid >> 2;
  const int wc = wid & 3;

  int bid = blockIdx.x;
  int swz = (bid & 7) * 64 + (bid >> 3);
  int m0 = (swz >> 3) * 256;
  int n0 = (swz & 7) * 256;

  const int xr = (lane & 7) << 4;
  const int cs0 = (((lane >> 4) << 4) ^ xr);
  const int cs1 = cs0 ^ 64;
  const int aBase = wr * 16384 + (lane & 15) * 128;
  const int bBase = 65536 + (wc >> 1) * 16384 + (wc & 1) * 8192 + (lane & 15) * 128;

  const int sidx0 = tid, sidx1 = tid + 512;
  const int srow0 = sidx0 >> 3, srow1 = sidx1 >> 3;
  const int scol0 = ((((sidx0 & 7) << 4) ^ ((srow0 & 7) << 4)) >> 1);
  const int scol1 = ((((sidx1 & 7) << 4) ^ ((srow1 & 7) << 4)) >> 1);
  const int d0 = sidx0 * 16, d1 = sidx1 * 16;

  f32x4 acc[8][4] = {};
  bf16x8 bq[4][2], pc[2][2], pn[2][2];

#define STAGE_A(buf, h_, kt)                                                          \
  {                                                                                   \
    gload_lds16(Ag + (size_t)(m0 + (h_)*128 + srow0) * 1024 + (kt) + scol0,           \
                smem + (buf)*32768 + (h_)*16384 + d0);                                \
    gload_lds16(Ag + (size_t)(m0 + (h_)*128 + srow1) * 1024 + (kt) + scol1,           \
                smem + (buf)*32768 + (h_)*16384 + d1);                                \
  }
#define STAGE_B(buf, h_, kt)                                                          \
  {                                                                                   \
    gload_lds16(Bg + (size_t)(n0 + (h_)*128 + srow0) * 1024 + (kt) + scol0,           \
                smem + 65536 + (buf)*32768 + (h_)*16384 + d0);                        \
    gload_lds16(Bg + (size_t)(n0 + (h_)*128 + srow1) * 1024 + (kt) + scol1,           \
                smem + 65536 + (buf)*32768 + (h_)*16384 + d1);                        \
  }
#define LDA(buf, f, s) (*(const bf16x8*)(smem + (buf)*32768 + aBase + (f)*2048 + ((s) ? cs1 : cs0)))
#define LDB(buf, g, s) (*(const bf16x8*)(smem + bBase + (buf)*32768 + (g)*2048 + ((s) ? cs1 : cs0)))
#define MFMA_(a, b, c) __builtin_amdgcn_mfma_f32_16x16x32_bf16(a, b, c, 0, 0, 0)
#define RD_PAIR(D, buf, f)                                                            \
  { D[0][0] = LDA(buf, f, 0); D[0][1] = LDA(buf, f, 1);                               \
    D[1][0] = LDA(buf, (f) + 1, 0); D[1][1] = LDA(buf, (f) + 1, 1); }
#define RD_BQ(buf)                                                                    \
  { _Pragma("unroll") for (int g = 0; g < 4; ++g) {                                   \
      bq[g][0] = LDB(buf, g, 0); bq[g][1] = LDB(buf, g, 1); } }
#define MM_PAIR(F0, P)                                                                \
  { _Pragma("unroll") for (int g = 0; g < 4; ++g) {                                   \
      acc[F0][g]       = MFMA_(P[0][0], bq[g][0], acc[F0][g]);                        \
      acc[(F0) + 1][g] = MFMA_(P[1][0], bq[g][0], acc[(F0) + 1][g]);                  \
      acc[F0][g]       = MFMA_(P[0][1], bq[g][1], acc[F0][g]);                        \
      acc[(F0) + 1][g] = MFMA_(P[1][1], bq[g][1], acc[(F0) + 1][g]); } }
#define BAR __builtin_amdgcn_s_barrier()
#define PRIO1 __builtin_amdgcn_s_setprio(1)
#define PRIO0 __builtin_amdgcn_s_setprio(0)

#define TILE(BUF, NBUF, T)                                                            \
  {                                                                                   \
    /* P0 */                                                                          \
    BAR;                                                                              \
    if ((T) < 15) { STAGE_A(NBUF, 0, ((T) + 1) * 64); STAGE_A(NBUF, 1, ((T) + 1) * 64); } \
    PRIO1; MM_PAIR(0, pc); PRIO0;                                                     \
    RD_PAIR(pn, BUF, 2);                                                              \
    /* P1 */                                                                          \
    BAR;                                                                              \
    PRIO1; MM_PAIR(2, pn); PRIO0;                                                     \
    RD_PAIR(pc, BUF, 4);                                                              \
    /* P2 */                                                                          \
    BAR;                                                                              \
    if ((T) < 14) STAGE_B(BUF, 0, ((T) + 2) * 64);                                    \
    PRIO1; MM_PAIR(4, pc); PRIO0;                                                     \
    RD_PAIR(pn, BUF, 6);                                                              \
    /* P3 */                                                                          \
    if ((T) < 14)       { asm volatile("s_waitcnt vmcnt(2)" ::: "memory"); }          \
    else if ((T) == 14) { asm volatile("s_waitcnt vmcnt(0)" ::: "memory"); }          \
    BAR;                                                                              \
    if ((T) < 14) STAGE_B(BUF, 1, ((T) + 2) * 64);                                    \
    PRIO1; MM_PAIR(6, pn); PRIO0;                                                     \
    if ((T) < 15) { RD_BQ(NBUF); RD_PAIR(pc, NBUF, 0); }                              \
  }

  STAGE_B(0, 0, 0); STAGE_B(0, 1, 0); STAGE_A(0, 0, 0); STAGE_A(0, 1, 0);
  STAGE_B(1, 0, 64); STAGE_B(1, 1, 64);
  asm volatile("s_waitcnt vmcnt(4)" ::: "memory");
  BAR;
  RD_BQ(0); RD_PAIR(pc, 0, 0);

  for (int t = 0; t < 14; t += 2) {
    TILE(0, 1, t);
    TILE(1, 0, t + 1);
  }
  TILE(0, 1, 14);
  TILE(1, 0, 15);

  // GLU epilogue: C/D layout col=lane&15, row=(lane>>4)*4+j
#pragma unroll
  for (int f = 0; f < 8; ++f) {
    int row = m0 + wr * 128 + f * 16 + ((lane >> 4) << 2);
#pragma unroll
    for (int g = 0; g < 4; ++g) {
      int col = n0 + wc * 64 + g * 16 + (lane & 15);
      int src = (col & 1) ? 1024 + (col >> 1) : (col >> 1);
      float bv = bias[src];
#pragma unroll
      for (int j = 0; j < 4; ++j) {
        float v = acc[f][g][j] + bv;
        float gt = __shfl_xor(v, 1);
        if (!(col & 1)) {
          float kv = v / (1.f + __expf(-gt));
          outp[(size_t)(row + j) * 1024 + (col >> 1)] = (bf16_t)kv;
        }
      }
    }
  }
#undef STAGE_A
#undef STAGE_B
#undef LDA
#undef LDB
#undef MFMA_
#undef RD_PAIR
#undef RD_BQ
#undef MM_PAIR
#undef BAR
#undef PRIO1
#undef PRIO0
#undef TILE
}

// ---------- GEMM2 + fused softmax: 128x128 tile -> bf16 weights [16384][512] ----------
__global__ __launch_bounds__(256, 2) void gemm128_sm(const bf16_t* __restrict__ Ag,
                                                     const bf16_t* __restrict__ Bg,
                                                     const float* __restrict__ bck,
                                                     bf16_t* __restrict__ Wout) {
  __shared__ bf16_t As[2][128 * 32];
  __shared__ bf16_t Bs[2][128 * 32];
  int tid = threadIdx.x;
  int lane = tid & 63;
  int wid = tid >> 6;
  int wr = wid >> 1, wc = wid & 1;
  int n0 = blockIdx.x * 128;
  int m0 = blockIdx.y * 128;

  f32x4 acc[4][4] = {};

#define STAGE(bufi, kt)                                                         \
  {                                                                             \
    _Pragma("unroll") for (int s_ = 0; s_ < 2; ++s_) {                          \
      int idx = (tid + s_ * 256) * 8;                                           \
      int row = idx >> 5;                                                       \
      int col = idx & 31;                                                       \
      gload_lds16(Ag + (size_t)(m0 + row) * 1024 + (kt) + col, &As[bufi][idx]); \
      gload_lds16(Bg + (size_t)(n0 + row) * 1024 + (kt) + col, &Bs[bufi][idx]); \
    }                                                                           \
  }

#define COMPUTE(bufi)                                                           \
  {                                                                             \
    int ko = (lane >> 4) * 8;                                                   \
    int rl = lane & 15;                                                         \
    bf16x8 af[4], bb[4];                                                        \
    _Pragma("unroll") for (int m_ = 0; m_ < 4; ++m_)                            \
        af[m_] = *(const bf16x8*)&As[bufi][(wr * 64 + m_ * 16 + rl) * 32 + ko]; \
    _Pragma("unroll") for (int n_ = 0; n_ < 4; ++n_)                            \
        bb[n_] = *(const bf16x8*)&Bs[bufi][(wc * 64 + n_ * 16 + rl) * 32 + ko]; \
    _Pragma("unroll") for (int m_ = 0; m_ < 4; ++m_)                            \
        _Pragma("unroll") for (int n_ = 0; n_ < 4; ++n_)                        \
            acc[m_][n_] = __builtin_amdgcn_mfma_f32_16x16x32_bf16(              \
                af[m_], bb[n_], acc[m_][n_], 0, 0, 0);                          \
  }

  STAGE(0, 0);
  __syncthreads();
  int buf = 0;
  for (int kt = 32; kt < 1024; kt += 32) {
    STAGE(buf ^ 1, kt);
    COMPUTE(buf);
    __syncthreads();
    buf ^= 1;
  }
  COMPUTE(buf);

  int s = lane & 15;
  int slotB = s + 16;
#pragma unroll
  for (int m_ = 0; m_ < 4; ++m_) {
    int row = m0 + wr * 64 + m_ * 16 + ((lane >> 4) << 2);
#pragma unroll
    for (int pp = 0; pp < 2; ++pp) {
      int colA = n0 + wc * 64 + pp * 32 + s;
      int hh = colA >> 5;
      float bvA = bck[hh * 31 + s];
      float bvB = (slotB < 31) ? bck[hh * 31 + slotB] : 0.f;
#pragma unroll
      for (int j = 0; j < 4; ++j) {
        float v0 = acc[m_][2 * pp][j] + bvA;
        float v1 = (slotB < 31) ? (acc[m_][2 * pp + 1][j] + bvB) : -1e30f;
        float mx = fmaxf(v0, v1);
        mx = fmaxf(mx, __shfl_xor(mx, 1));
        mx = fmaxf(mx, __shfl_xor(mx, 2));
        mx = fmaxf(mx, __shfl_xor(mx, 4));
        mx = fmaxf(mx, __shfl_xor(mx, 8));
        float e0 = __expf(v0 - mx);
        float e1 = (slotB < 31) ? __expf(v1 - mx) : 0.f;
        float ss = e0 + e1;
        ss += __shfl_xor(ss, 1);
        ss += __shfl_xor(ss, 2);
        ss += __shfl_xor(ss, 4);
        ss += __shfl_xor(ss, 8);
        float inv = 1.f / ss;
        Wout[(size_t)(row + j) * 512 + colA] = (bf16_t)(e0 * inv);
        Wout[(size_t)(row + j) * 512 + colA + 16] = (bf16_t)(e1 * inv);
      }
    }
  }
#undef STAGE
#undef COMPUTE
}

// ---------- depthwise dynamic conv + bias + residual ----------
__global__ __launch_bounds__(256) void conv_kernel(const bf16_t* __restrict__ Kin,
                                                   const bf16_t* __restrict__ Wq,
                                                   const float* __restrict__ x,
                                                   const float* __restrict__ conv_bias,
                                                   float* __restrict__ out) {
  __shared__ bf16_t ks[94][64];
  __shared__ float wls[64][36];   // pad 32->36: breaks 16-way bank conflict on writes
  int tid = threadIdx.x;
  int t0 = blockIdx.x * 64;
  int hh = blockIdx.y;
  int b = blockIdx.z;

  for (int i = tid; i < 94 * 8; i += 256) {
    int r = i >> 3;
    int seg = (i & 7) * 8;
    int t = t0 - 15 + r;
    bf16x8 v = {};
    if (t >= 0 && t < 2048)
      v = *(const bf16x8*)&Kin[((size_t)b * 2048 + t) * 1024 + hh * 64 + seg];
    *(bf16x8*)&ks[r][seg] = v;
  }
  {
    int tok = tid >> 2, part = tid & 3;
    bf16x8 wv8 = *(const bf16x8*)&Wq[((size_t)b * 2048 + t0 + tok) * 512 + hh * 32 + part * 8];
#pragma unroll
    for (int j = 0; j < 8; ++j) wls[tok][part * 8 + j] = (float)wv8[j];
  }
  __syncthreads();

  int lane = tid & 63;
  int tq = tid >> 6;
  float win[46];
#pragma unroll
  for (int j = 0; j < 46; ++j) win[j] = (float)ks[tq * 16 + j][lane];
  float cb = conv_bias[hh * 64 + lane];
#pragma unroll
  for (int j = 0; j < 16; ++j) {
    int trow = tq * 16 + j;
    float wv[31];
#pragma unroll
    for (int i4 = 0; i4 < 7; ++i4) {
      f32x4 w4 = *(const f32x4*)&wls[trow][i4 * 4];
      wv[i4 * 4 + 0] = w4[0]; wv[i4 * 4 + 1] = w4[1];
      wv[i4 * 4 + 2] = w4[2]; wv[i4 * 4 + 3] = w4[3];
    }
    wv[28] = wls[trow][28]; wv[29] = wls[trow][29]; wv[30] = wls[trow][30];
    float a = 0.f;
#pragma unroll
    for (int i = 0; i < 31; ++i) a += wv[i] * win[j + i];
    size_t off = ((size_t)b * 2048 + t0 + trow) * 1024 + hh * 64 + lane;
    out[off] = a + cb + x[off];
  }
}

extern "C" void kernel_launch(void* const* d_in, const int* in_sizes, int n_in,
                              void* d_out, int out_size, void* d_ws, size_t ws_size,
                              hipStream_t stream) {
  const float* x         = (const float*)d_in[0];
  const float* Wk        = (const float*)d_in[1];
  const float* bk        = (const float*)d_in[2];
  const float* Wck       = (const float*)d_in[3];
  const float* bck       = (const float*)d_in[4];
  const float* gamma     = (const float*)d_in[5];
  const float* beta      = (const float*)d_in[6];
  const float* conv_bias = (const float*)d_in[7];
  float* out = (float*)d_out;

  char* ws = (char*)d_ws;
  bf16_t* h      = (bf16_t*)(ws);                  // 32MB
  bf16_t* kbuf   = (bf16_t*)(ws + (33554432));     // 32MB
  bf16_t* WT1    = (bf16_t*)(ws + (67108864));     // 4MB
  bf16_t* WT2    = (bf16_t*)(ws + (71303168));     // 1MB
  bf16_t* Wq     = (bf16_t*)(ws + (72351744));     // 16MB softmaxed weights

  hipFuncSetAttribute((const void*)gemm256_glu,
                      hipFuncAttributeMaxDynamicSharedMemorySize, 131072);

  prep_wk<<<dim3(32, 16), 256, 0, stream>>>(Wk, WT1);
  prep_wck<<<dim3(8, 16), 256, 0, stream>>>(Wck, WT2);
  ln_kernel<<<4096, 256, 0, stream>>>(x, gamma, beta, h);
  gemm256_glu<<<512, 512, 131072, stream>>>(h, WT1, bk, kbuf);
  gemm128_sm<<<dim3(4, 128), 256, 0, stream>>>(kbuf, WT2, bck, Wq);
  conv_kernel<<<dim3(32, 16, 8), 256, 0, stream>>>(kbuf, Wq, x, conv_bias, out);
}